// Round 2
// baseline (424.571 us; speedup 1.0000x reference)
//
#include <hip/hip_runtime.h>

// out[d] = sum_{e: dst[e]==d} x[src[e]]   (N=100k, E=1.6M, D=32 f32)
//
// Round-11: bucket-major bin + count-gated flush (2-kernel graph, 111us).
// Round-12 (cooperative fusion) FAILED: hipLaunchCooperativeKernel is not
// graph-capturable (timed graph silently fell back; coop kernel itself was
// latency-bound at 268us). Reverted.
// Round-13: (1) kill the cnt matrix -- 5-bit sub-bin count embedded in bin
// slot-0 bits[24:28] (entry only uses 24 bits); gather read of cnt was 512
// uncoalesced lines/block = ~25MB HBM fetch. (2) gather accumulates straight
// into an LDS s_out[128][32] tile via ds_add_f32 (rotation-swizzled to break
// 8-way bank conflicts) -- removes count/rank/sort passes and the per-node
// degree imbalance entirely.

#define D_FEAT 32
#define BKT_SHIFT 7
#define BKT_NODES 128
#define CAPSH 4               // 16 slots per sub-bin (64B = 4 quads)
#define CAP (1 << CAPSH)
#define ECAP 4096             // packed entries per gather flush
#define OVFB 512              // overflow pairs per scatter block
typedef unsigned int u32;

// One block per edge-chunk. Stage sub-bins in LDS, gated bucket-major flush.
// dynamic LDS: s_stage[nb*CAP] | s_cur[nb]
__global__ void __launch_bounds__(512)
k_scatter6(const int* __restrict__ src, const int* __restrict__ dst,
           u32* __restrict__ bin, u32* __restrict__ ovfb, u32* __restrict__ ovfn,
           int n_edges, int nb, int nsub, int chunk) {
    extern __shared__ u32 smem[];
    u32* s_stage = smem;                           // nb*CAP words
    u32* s_cur   = smem + ((size_t)nb << CAPSH);   // nb words
    __shared__ u32 s_ovf_n;
    int blk = blockIdx.x, t = threadIdx.x;
    for (int i = t; i < nb; i += 512) s_cur[i] = 0u;
    if (t == 0) s_ovf_n = 0u;
    __syncthreads();
    int beg = blk * chunk, end = min(beg + chunk, n_edges);
    for (int e = beg + t; e < end; e += 512) {
        u32 d = (u32)dst[e];
        u32 b = d >> BKT_SHIFT;
        u32 pos = atomicAdd(&s_cur[b], 1u);          // LDS-only RMW
        u32 packed = (u32)src[e] | ((d & (BKT_NODES - 1)) << 17);
        if (pos < (u32)CAP) {
            s_stage[(b << CAPSH) + pos] = packed;
        } else {
            u32 g = atomicAdd(&s_ovf_n, 1u);         // ~never taken
            if (g < (u32)OVFB) {
                ovfb[((size_t)blk * OVFB + g) * 2]     = packed;
                ovfb[((size_t)blk * OVFB + g) * 2 + 1] = (u32)b;
            }
        }
    }
    __syncthreads();
    // bucket-major flush: bin[b][blk][slot]. quad0 ALWAYS written, count in
    // .x bits[24:28]; quads 1..3 gated on count.
    {
        const uint4* sq = (const uint4*)s_stage;
        uint4* gq = (uint4*)bin;
        int nquads = nb << (CAPSH - 2);
        for (int i = t; i < nquads; i += 512) {
            int b  = i >> (CAPSH - 2);
            int k4 = i & ((1 << (CAPSH - 2)) - 1);
            u32 cn = min(s_cur[b], (u32)CAP);
            size_t gidx = (((size_t)b * nsub + blk) << (CAPSH - 2)) + k4;
            if (k4 == 0) {
                uint4 v = sq[i];
                v.x = (v.x & 0x00FFFFFFu) | (cn << 24);
                gq[gidx] = v;
            } else if ((u32)(k4 << 2) < cn) {
                gq[gidx] = sq[i];
            }
        }
    }
    if (t == 0) ovfn[blk] = min(s_ovf_n, (u32)OVFB);
}

// One block per bucket: counts from bin quad0 words -> shfl-scan ->
// sequential gated pack -> direct ds_add_f32 accumulation into s_out tile.
__global__ void __launch_bounds__(512)
k_gather6(const float* __restrict__ x, const u32* __restrict__ bin,
          const u32* __restrict__ ovfb, const u32* __restrict__ ovfn,
          float* __restrict__ out, int n_nodes, int nb, int nsub) {
    __shared__ u32 s_cnt[512];
    __shared__ u32 s_base[513];
    __shared__ u32 s_wsum[8];
    __shared__ u32 s_ent[ECAP];
    __shared__ float s_out[BKT_NODES * D_FEAT];   // 16 KB accumulation tile
    __shared__ u32 s_has;
    int b = blockIdx.x, t = threadIdx.x;
    int lane = t & 63, wid = t >> 6;
    int node0 = b * BKT_NODES;
    const float4* x4 = (const float4*)x;
    const uint4* bin4 = (const uint4*)bin;
    int q = t & 7;                         // float4 column within x row
    int grp = t >> 3;                      // 64 groups of 8 lanes

    // zero the accumulation tile (covered by the scan's syncthreads)
    for (int i = t; i < BKT_NODES * D_FEAT; i += 512) s_out[i] = 0.f;

    // sub-bin counts straight from bin quad0 words (lines re-used by pack)
    u32 c = 0u;
    if (t < nsub) {
        u32 w = bin[((size_t)b * nsub + t) << CAPSH];
        c = (w >> 24) & 0x1Fu;
    }
    u32 myovf = (t < nsub) ? ovfn[t] : 0u;
    s_cnt[t] = c;
    if (t == 0) s_has = 0u;
    // exclusive scan (wave shfl + cross-wave fix)
    u32 s = c;
    #pragma unroll
    for (int off = 1; off < 64; off <<= 1) {
        u32 y = __shfl_up(s, off, 64);
        if (lane >= off) s += y;
    }
    if (lane == 63) s_wsum[wid] = s;
    __syncthreads();
    if (t == 0) {
        u32 run = 0u;
        #pragma unroll
        for (int w = 0; w < 8; ++w) { u32 v = s_wsum[w]; s_wsum[w] = run; run += v; }
    }
    if (myovf) atomicOr(&s_has, 1u);
    __syncthreads();
    u32 incl = s + s_wsum[wid];
    s_base[t] = incl - c;                  // exclusive
    if (t == 511) s_base[512] = incl;
    __syncthreads();

    int subA = 0;
    u32 baseA = 0u;
    while (subA < nsub) {
        // largest subB with base[subB]-baseA <= ECAP (usually subB == nsub)
        int lo = subA + 1, hi = nsub;
        while (lo < hi) {
            int mid = (lo + hi + 1) >> 1;
            if (s_base[mid] - baseA <= (u32)ECAP) lo = mid; else hi = mid - 1;
        }
        int subB = lo;
        int m = (int)(s_base[subB] - baseA);

        // pack sub-bins [subA,subB): sequential gated uint4 stream
        {
            int quads = (subB - subA) << (CAPSH - 2);
            size_t qbase = ((size_t)b * nsub + subA) << (CAPSH - 2);
            for (int i = t; i < quads; i += 512) {
                int sub = subA + (i >> (CAPSH - 2));
                int slot0 = (i & ((1 << (CAPSH - 2)) - 1)) << 2;
                u32 cn = s_cnt[sub];
                if ((u32)slot0 < cn) {
                    uint4 v = bin4[qbase + i];
                    u32 base = (s_base[sub] - baseA) + slot0;
                    s_ent[base] = v.x;
                    if ((u32)(slot0 + 1) < cn) s_ent[base + 1] = v.y;
                    if ((u32)(slot0 + 2) < cn) s_ent[base + 2] = v.z;
                    if ((u32)(slot0 + 3) < cn) s_ent[base + 3] = v.w;
                }
            }
        }
        __syncthreads();

        // accumulate: 8 lanes share one 128B x row; ds_add_f32 into s_out.
        // float4-rotation by (dl&7) breaks the would-be 8-way bank conflict.
        #pragma unroll 4
        for (int i = grp; i < m; i += 64) {
            u32 p = s_ent[i];                         // LDS broadcast (8 lanes)
            u32 sidx = p & 0x1FFFFu;
            u32 dl = (p >> 17) & 127u;
            float4 xv = x4[(size_t)sidx * 8 + q];
            int f4 = (q + (int)(dl & 7)) & 7;
            float* so = s_out + dl * D_FEAT + f4 * 4;
            atomicAdd(so + 0, xv.x);
            atomicAdd(so + 1, xv.y);
            atomicAdd(so + 2, xv.z);
            atomicAdd(so + 3, xv.w);
        }
        __syncthreads();
        subA = subB;
        baseA = s_base[subB];
    }

    // replay per-block overflow lists (normally all empty)
    if (s_has) {
        for (int sub = 0; sub < nsub; ++sub) {
            u32 n = ovfn[sub];
            for (u32 i = 0; i < n; ++i) {
                u32 ob = ovfb[((size_t)sub * OVFB + i) * 2 + 1];
                if (ob == (u32)b) {
                    u32 p = ovfb[((size_t)sub * OVFB + i) * 2];
                    u32 dl = (p >> 17) & 127u;
                    if (grp == (int)(dl >> 1)) {      // exactly one 8-lane group
                        float4 xv = x4[(size_t)(p & 0x1FFFFu) * 8 + q];
                        int f4 = (q + (int)(dl & 7)) & 7;
                        float* so = s_out + dl * D_FEAT + f4 * 4;
                        atomicAdd(so + 0, xv.x);
                        atomicAdd(so + 1, xv.y);
                        atomicAdd(so + 2, xv.z);
                        atomicAdd(so + 3, xv.w);
                    }
                }
            }
        }
        __syncthreads();
    }

    // write-out: un-rotate, coalesced float4 stores
    {
        const float4* so4 = (const float4*)s_out;
        float4* o4 = (float4*)out;
        for (int idx = t; idx < BKT_NODES * 8; idx += 512) {
            int node = idx >> 3, qo = idx & 7;
            if (node0 + node < n_nodes) {
                int slot = (qo + (node & 7)) & 7;
                o4[((size_t)(node0 + node)) * 8 + qo] = so4[node * 8 + slot];
            }
        }
    }
}

// ---------------- last-resort atomic path ----------------

__global__ void __launch_bounds__(256)
mp_zero_kernel(float* __restrict__ out, int n) {
    int i = blockIdx.x * blockDim.x + threadIdx.x;
    if (i < n) out[i] = 0.0f;
}

__global__ void __launch_bounds__(256)
mp_scatter_kernel(const float* __restrict__ x, const int* __restrict__ src,
                  const int* __restrict__ dst, float* __restrict__ out,
                  int n_edges) {
    int idx = blockIdx.x * blockDim.x + threadIdx.x;
    if (idx >= n_edges * 8) return;
    int e = idx >> 3;
    int c = idx & 7;
    const float4 v = *reinterpret_cast<const float4*>(x + (size_t)src[e] * D_FEAT + c * 4);
    float* o = out + (size_t)dst[e] * D_FEAT + c * 4;
    unsafeAtomicAdd(o + 0, v.x);
    unsafeAtomicAdd(o + 1, v.y);
    unsafeAtomicAdd(o + 2, v.z);
    unsafeAtomicAdd(o + 3, v.w);
}

// ==================== launch ====================

extern "C" void kernel_launch(void* const* d_in, const int* in_sizes, int n_in,
                              void* d_out, int out_size, void* d_ws, size_t ws_size,
                              hipStream_t stream) {
    const float* x = (const float*)d_in[0];
    const int* edge_index = (const int*)d_in[1];
    int n_edges = in_sizes[1] / 2;
    const int* src = edge_index;            // row 0: source j
    const int* dst = edge_index + n_edges;  // row 1: target i
    float* out = (float*)d_out;
    int n_nodes = out_size / D_FEAT;

    int nb = (n_nodes + BKT_NODES - 1) >> BKT_SHIFT;     // 782

    // dynamic LDS for scatter: nb*CAP stage + nb cursors
    size_t sc_lds = ((size_t)nb * CAP + nb) * sizeof(u32);   // 53.2 KB @ nb=782

    if (n_nodes <= (1 << 17) && sc_lds <= 64 * 1024) {
        const int ncand[3] = {512, 384, 256};
        for (int ci = 0; ci < 3; ++ci) {
            int nsub = ncand[ci];
            int chunk = (n_edges + nsub - 1) / nsub;
            size_t need = (512                                // ovfn
                           + 2 * (size_t)nsub * OVFB          // ovfb
                           + (((size_t)nb * nsub) << CAPSH))  // bin (bucket-major)
                          * sizeof(u32);
            if (need > ws_size) continue;

            u32* ovfn = (u32*)d_ws;
            u32* ovfb = ovfn + 512;
            u32* bin  = ovfb + 2 * (size_t)nsub * OVFB;

            k_scatter6<<<nsub, 512, sc_lds, stream>>>(src, dst, bin, ovfb, ovfn,
                                                      n_edges, nb, nsub, chunk);
            k_gather6<<<nb, 512, 0, stream>>>(x, bin, ovfb, ovfn, out,
                                              n_nodes, nb, nsub);
            return;
        }
    }

    // last-resort: atomic path
    mp_zero_kernel<<<(out_size + 255) / 256, 256, 0, stream>>>(out, out_size);
    int total_thr = n_edges * 8;
    mp_scatter_kernel<<<(total_thr + 255) / 256, 256, 0, stream>>>(x, src, dst, out, n_edges);
}

// Round 4
// 119.068 us; speedup vs baseline: 3.5658x; 3.5658x over previous
//
#include <hip/hip_runtime.h>

// out[d] = sum_{e: dst[e]==d} x[src[e]]   (N=100k, E=1.6M, D=32 f32)
//
// Round-11: bucket-major bin + count-gated flush, sort-based gather (111us).
// Round-12 (coop fusion) FAILED: not graph-capturable.
// Round-13 (ds_add_f32 tile) FAILED: dl*32 vanishes mod 32 banks -> 8-way
// conflict on every ds_add wave; gather 350us.
// Round-14: sort-based gather + counts embedded in bin quad0 bits[24:28]
// (kills the cnt matrix: -25MB uncoalesced gather fetch). NT stores for the
// bin flush via ext_vector_type (HIP uint4 class rejected by the builtin).
// Timing model (r13 calibration): dur = ~42us harness poison-fill +
// scatter(~30us) + gather(~35us).

#define D_FEAT 32
#define BKT_SHIFT 7
#define BKT_NODES 128
#define CAPSH 4               // 16 slots per sub-bin (64B = 4 quads)
#define CAP (1 << CAPSH)
#define ECAP 4096             // packed entries per gather flush
#define OVFB 512              // overflow pairs per scatter block
typedef unsigned int u32;
typedef u32 u32x4 __attribute__((ext_vector_type(4)));

// One block per edge-chunk. Stage sub-bins in LDS, gated bucket-major flush.
// dynamic LDS: s_stage[nb*CAP] | s_cur[nb]
__global__ void __launch_bounds__(512)
k_scatter6(const int* __restrict__ src, const int* __restrict__ dst,
           u32* __restrict__ bin, u32* __restrict__ ovfb, u32* __restrict__ ovfn,
           int n_edges, int nb, int nsub, int chunk) {
    extern __shared__ u32 smem[];
    u32* s_stage = smem;                           // nb*CAP words
    u32* s_cur   = smem + ((size_t)nb << CAPSH);   // nb words
    __shared__ u32 s_ovf_n;
    int blk = blockIdx.x, t = threadIdx.x;
    for (int i = t; i < nb; i += 512) s_cur[i] = 0u;
    if (t == 0) s_ovf_n = 0u;
    __syncthreads();
    int beg = blk * chunk, end = min(beg + chunk, n_edges);
    for (int e = beg + t; e < end; e += 512) {
        u32 d = (u32)dst[e];
        u32 b = d >> BKT_SHIFT;
        u32 pos = atomicAdd(&s_cur[b], 1u);          // LDS-only RMW
        u32 packed = (u32)src[e] | ((d & (BKT_NODES - 1)) << 17);
        if (pos < (u32)CAP) {
            s_stage[(b << CAPSH) + pos] = packed;
        } else {
            u32 g = atomicAdd(&s_ovf_n, 1u);         // ~never taken
            if (g < (u32)OVFB) {
                ovfb[((size_t)blk * OVFB + g) * 2]     = packed;
                ovfb[((size_t)blk * OVFB + g) * 2 + 1] = (u32)b;
            }
        }
    }
    __syncthreads();
    // bucket-major flush: bin[b][blk][slot]. quad0 ALWAYS written, count in
    // .x bits[24:28]; quads 1..3 gated on count. NT stores: consumed by the
    // gather kernel (likely another XCD) -- don't cache in producer L2.
    {
        const u32x4* sq = (const u32x4*)s_stage;
        u32x4* gq = (u32x4*)bin;
        int nquads = nb << (CAPSH - 2);
        for (int i = t; i < nquads; i += 512) {
            int b  = i >> (CAPSH - 2);
            int k4 = i & ((1 << (CAPSH - 2)) - 1);
            u32 cn = min(s_cur[b], (u32)CAP);
            size_t gidx = (((size_t)b * nsub + blk) << (CAPSH - 2)) + k4;
            if (k4 == 0) {
                u32x4 v = sq[i];
                v.x = (v.x & 0x00FFFFFFu) | (cn << 24);
                __builtin_nontemporal_store(v, &gq[gidx]);
            } else if ((u32)(k4 << 2) < cn) {
                u32x4 v = sq[i];
                __builtin_nontemporal_store(v, &gq[gidx]);
            }
        }
    }
    if (t == 0) ovfn[blk] = min(s_ovf_n, (u32)OVFB);
}

// One block per bucket: counts from bin quad0 words -> shfl-scan ->
// sequential gated pack -> sort by dlocal (shfl-scan) -> register
// accumulate (4-way unrolled).
__global__ void __launch_bounds__(512)
k_gather7(const float* __restrict__ x, const u32* __restrict__ bin,
          const u32* __restrict__ ovfb, const u32* __restrict__ ovfn,
          float* __restrict__ out, int n_nodes, int nb, int nsub) {
    __shared__ u32 s_cnt[512];
    __shared__ u32 s_base[513];
    __shared__ u32 s_wsum[8];
    __shared__ u32 s_ent[ECAP];
    __shared__ u32 s_srt[ECAP];
    __shared__ u32 s_off[BKT_NODES + 1];
    __shared__ u32 s_cur[BKT_NODES];
    __shared__ u32 s_has;
    int b = blockIdx.x, t = threadIdx.x;
    int lane = t & 63, wid = t >> 6;
    int node0 = b * BKT_NODES;
    const float4* x4 = (const float4*)x;
    const uint4* bin4 = (const uint4*)bin;
    int q = t & 7;
    int n0 = t >> 3;                       // nodes n0 and n0+64
    float4 a0 = make_float4(0.f, 0.f, 0.f, 0.f);
    float4 a1 = make_float4(0.f, 0.f, 0.f, 0.f);

    // sub-bin counts from bin quad0 words (same lines the pack re-reads)
    u32 c = 0u;
    if (t < nsub) {
        u32 w = bin[((size_t)b * nsub + t) << CAPSH];
        c = (w >> 24) & 0x1Fu;
    }
    u32 myovf = (t < nsub) ? ovfn[t] : 0u;
    s_cnt[t] = c;
    if (t == 0) s_has = 0u;
    // exclusive scan (wave shfl + cross-wave fix)
    u32 s = c;
    #pragma unroll
    for (int off = 1; off < 64; off <<= 1) {
        u32 y = __shfl_up(s, off, 64);
        if (lane >= off) s += y;
    }
    if (lane == 63) s_wsum[wid] = s;
    __syncthreads();
    if (t == 0) {
        u32 run = 0u;
        #pragma unroll
        for (int w = 0; w < 8; ++w) { u32 v = s_wsum[w]; s_wsum[w] = run; run += v; }
    }
    if (myovf) atomicOr(&s_has, 1u);
    __syncthreads();
    u32 incl = s + s_wsum[wid];
    s_base[t] = incl - c;                  // exclusive
    if (t == 511) s_base[512] = incl;
    __syncthreads();

    int subA = 0;
    u32 baseA = 0u;
    while (subA < nsub) {
        // largest subB with base[subB]-baseA <= ECAP
        int lo = subA + 1, hi = nsub;
        while (lo < hi) {
            int mid = (lo + hi + 1) >> 1;
            if (s_base[mid] - baseA <= (u32)ECAP) lo = mid; else hi = mid - 1;
        }
        int subB = lo;
        int m = (int)(s_base[subB] - baseA);

        // pack sub-bins [subA,subB): sequential gated uint4 stream.
        // slot-0 words carry count bits [24:28]; masked at use-sites below.
        {
            int quads = (subB - subA) << (CAPSH - 2);
            size_t qbase = ((size_t)b * nsub + subA) << (CAPSH - 2);
            for (int i = t; i < quads; i += 512) {
                int sub = subA + (i >> (CAPSH - 2));
                int slot0 = (i & ((1 << (CAPSH - 2)) - 1)) << 2;
                u32 cn = s_cnt[sub];
                if ((u32)slot0 < cn) {
                    uint4 v = bin4[qbase + i];
                    u32 base = (s_base[sub] - baseA) + slot0;
                    s_ent[base] = v.x;
                    if ((u32)(slot0 + 1) < cn) s_ent[base + 1] = v.y;
                    if ((u32)(slot0 + 2) < cn) s_ent[base + 2] = v.z;
                    if ((u32)(slot0 + 3) < cn) s_ent[base + 3] = v.w;
                }
            }
        }
        if (t < BKT_NODES) s_cur[t] = 0u;
        __syncthreads();

        // count by dlocal (mask: slot-0 entries carry count bits above 24)
        for (int i = t; i < m; i += 512) atomicAdd(&s_cur[(s_ent[i] >> 17) & 127u], 1u);
        __syncthreads();

        // 128-entry exclusive scan by wave 0 (2 entries/lane, shfl)
        if (wid == 0) {
            u32 v0 = s_cur[2 * lane], v1 = s_cur[2 * lane + 1];
            u32 ps = v0 + v1;
            #pragma unroll
            for (int off = 1; off < 64; off <<= 1) {
                u32 y = __shfl_up(ps, off, 64);
                if (lane >= off) ps += y;
            }
            u32 ex = ps - (v0 + v1);
            s_off[2 * lane] = ex;     s_cur[2 * lane] = ex;
            s_off[2 * lane + 1] = ex + v0; s_cur[2 * lane + 1] = ex + v0;
            if (lane == 63) s_off[BKT_NODES] = ps;
        }
        __syncthreads();

        // rank into s_srt
        for (int i = t; i < m; i += 512) {
            u32 p = s_ent[i];
            u32 pos = atomicAdd(&s_cur[(p >> 17) & 127u], 1u);
            s_srt[pos] = p & 0x1FFFFu;
        }
        __syncthreads();

        // accumulate: 8 lanes share one 128B x-row; 4-way unroll for MLP
        {
            u32 j = s_off[n0], j1 = s_off[n0 + 1];
            for (; j + 3 < j1; j += 4) {
                float4 xa = x4[(size_t)s_srt[j] * 8 + q];
                float4 xb = x4[(size_t)s_srt[j + 1] * 8 + q];
                float4 xc = x4[(size_t)s_srt[j + 2] * 8 + q];
                float4 xd = x4[(size_t)s_srt[j + 3] * 8 + q];
                a0.x += xa.x + xb.x + xc.x + xd.x;
                a0.y += xa.y + xb.y + xc.y + xd.y;
                a0.z += xa.z + xb.z + xc.z + xd.z;
                a0.w += xa.w + xb.w + xc.w + xd.w;
            }
            for (; j < j1; ++j) {
                float4 xa = x4[(size_t)s_srt[j] * 8 + q];
                a0.x += xa.x; a0.y += xa.y; a0.z += xa.z; a0.w += xa.w;
            }
            j = s_off[n0 + 64]; j1 = s_off[n0 + 65];
            for (; j + 3 < j1; j += 4) {
                float4 xa = x4[(size_t)s_srt[j] * 8 + q];
                float4 xb = x4[(size_t)s_srt[j + 1] * 8 + q];
                float4 xc = x4[(size_t)s_srt[j + 2] * 8 + q];
                float4 xd = x4[(size_t)s_srt[j + 3] * 8 + q];
                a1.x += xa.x + xb.x + xc.x + xd.x;
                a1.y += xa.y + xb.y + xc.y + xd.y;
                a1.z += xa.z + xb.z + xc.z + xd.z;
                a1.w += xa.w + xb.w + xc.w + xd.w;
            }
            for (; j < j1; ++j) {
                float4 xa = x4[(size_t)s_srt[j] * 8 + q];
                a1.x += xa.x; a1.y += xa.y; a1.z += xa.z; a1.w += xa.w;
            }
        }
        __syncthreads();
        subA = subB;
        baseA = s_base[subB];
    }

    // replay per-block overflow lists (normally all empty)
    if (s_has) {
        for (int sub = 0; sub < nsub; ++sub) {
            u32 n = ovfn[sub];
            for (u32 i = 0; i < n; ++i) {
                u32 ob = ovfb[((size_t)sub * OVFB + i) * 2 + 1];
                if (ob == (u32)b) {
                    u32 p = ovfb[((size_t)sub * OVFB + i) * 2];
                    u32 dl = (p >> 17) & 127u;
                    if (dl == (u32)n0 || dl == (u32)(n0 + 64)) {
                        float4 xv = x4[(size_t)(p & 0x1FFFFu) * 8 + q];
                        if (dl == (u32)n0) { a0.x += xv.x; a0.y += xv.y; a0.z += xv.z; a0.w += xv.w; }
                        else               { a1.x += xv.x; a1.y += xv.y; a1.z += xv.z; a1.w += xv.w; }
                    }
                }
            }
        }
    }

    float4* o4 = (float4*)out;
    if (node0 + n0 < n_nodes)      o4[(size_t)node0 * 8 + t] = a0;
    if (node0 + n0 + 64 < n_nodes) o4[(size_t)node0 * 8 + 512 + t] = a1;
}

// ---------------- last-resort atomic path ----------------

__global__ void __launch_bounds__(256)
mp_zero_kernel(float* __restrict__ out, int n) {
    int i = blockIdx.x * blockDim.x + threadIdx.x;
    if (i < n) out[i] = 0.0f;
}

__global__ void __launch_bounds__(256)
mp_scatter_kernel(const float* __restrict__ x, const int* __restrict__ src,
                  const int* __restrict__ dst, float* __restrict__ out,
                  int n_edges) {
    int idx = blockIdx.x * blockDim.x + threadIdx.x;
    if (idx >= n_edges * 8) return;
    int e = idx >> 3;
    int c = idx & 7;
    const float4 v = *reinterpret_cast<const float4*>(x + (size_t)src[e] * D_FEAT + c * 4);
    float* o = out + (size_t)dst[e] * D_FEAT + c * 4;
    unsafeAtomicAdd(o + 0, v.x);
    unsafeAtomicAdd(o + 1, v.y);
    unsafeAtomicAdd(o + 2, v.z);
    unsafeAtomicAdd(o + 3, v.w);
}

// ==================== launch ====================

extern "C" void kernel_launch(void* const* d_in, const int* in_sizes, int n_in,
                              void* d_out, int out_size, void* d_ws, size_t ws_size,
                              hipStream_t stream) {
    const float* x = (const float*)d_in[0];
    const int* edge_index = (const int*)d_in[1];
    int n_edges = in_sizes[1] / 2;
    const int* src = edge_index;            // row 0: source j
    const int* dst = edge_index + n_edges;  // row 1: target i
    float* out = (float*)d_out;
    int n_nodes = out_size / D_FEAT;

    int nb = (n_nodes + BKT_NODES - 1) >> BKT_SHIFT;     // 782

    // dynamic LDS for scatter: nb*CAP stage + nb cursors
    size_t sc_lds = ((size_t)nb * CAP + nb) * sizeof(u32);   // 53.2 KB @ nb=782

    if (n_nodes <= (1 << 17) && sc_lds <= 64 * 1024) {
        const int ncand[3] = {512, 384, 256};
        for (int ci = 0; ci < 3; ++ci) {
            int nsub = ncand[ci];
            int chunk = (n_edges + nsub - 1) / nsub;
            size_t need = (512                                // ovfn
                           + 2 * (size_t)nsub * OVFB          // ovfb
                           + (((size_t)nb * nsub) << CAPSH))  // bin (bucket-major)
                          * sizeof(u32);
            if (need > ws_size) continue;

            u32* ovfn = (u32*)d_ws;
            u32* ovfb = ovfn + 512;
            u32* bin  = ovfb + 2 * (size_t)nsub * OVFB;

            k_scatter6<<<nsub, 512, sc_lds, stream>>>(src, dst, bin, ovfb, ovfn,
                                                      n_edges, nb, nsub, chunk);
            k_gather7<<<nb, 512, 0, stream>>>(x, bin, ovfb, ovfn, out,
                                              n_nodes, nb, nsub);
            return;
        }
    }

    // last-resort: atomic path
    mp_zero_kernel<<<(out_size + 255) / 256, 256, 0, stream>>>(out, out_size);
    int total_thr = n_edges * 8;
    mp_scatter_kernel<<<(total_thr + 255) / 256, 256, 0, stream>>>(x, src, dst, out, n_edges);
}

// Round 5
// 113.218 us; speedup vs baseline: 3.7500x; 1.0517x over previous
//
#include <hip/hip_runtime.h>

// out[d] = sum_{e: dst[e]==d} x[src[e]]   (N=100k, E=1.6M, D=32 f32)
//
// Round-11: bucket-major bin + count-gated flush, sort-based gather (111us).
// Round-12 (coop fusion) FAILED: not graph-capturable.
// Round-13 (ds_add_f32 tile) FAILED: dl*32 vanishes mod 32 banks -> 8-way
// conflict on every ds_add wave; gather 350us.
// Round-14 (counts-in-quad0 + NT stores) REGRESSED to 119us. NT stores on
// the bin flush bypass L2 retention -> gather pays HBM for every bin line.
// Round-15: A/B -- same as r14 but plain stores. counts-in-quad0 retained
// (count word rides in the same 64B line as the sub-bin data; pack re-reads
// that line anyway, so the old separate 25MB cnt-matrix read is still dead).
// Timing model (r13 calibration): dur = ~42us harness poison-fill +
// scatter(~30us) + gather(~35us).

#define D_FEAT 32
#define BKT_SHIFT 7
#define BKT_NODES 128
#define CAPSH 4               // 16 slots per sub-bin (64B = 1 line = 4 quads)
#define CAP (1 << CAPSH)
#define ECAP 4096             // packed entries per gather flush
#define OVFB 512              // overflow pairs per scatter block
typedef unsigned int u32;

// One block per edge-chunk. Stage sub-bins in LDS, gated bucket-major flush.
// dynamic LDS: s_stage[nb*CAP] | s_cur[nb]
__global__ void __launch_bounds__(512)
k_scatter6(const int* __restrict__ src, const int* __restrict__ dst,
           u32* __restrict__ bin, u32* __restrict__ ovfb, u32* __restrict__ ovfn,
           int n_edges, int nb, int nsub, int chunk) {
    extern __shared__ u32 smem[];
    u32* s_stage = smem;                           // nb*CAP words
    u32* s_cur   = smem + ((size_t)nb << CAPSH);   // nb words
    __shared__ u32 s_ovf_n;
    int blk = blockIdx.x, t = threadIdx.x;
    for (int i = t; i < nb; i += 512) s_cur[i] = 0u;
    if (t == 0) s_ovf_n = 0u;
    __syncthreads();
    int beg = blk * chunk, end = min(beg + chunk, n_edges);
    for (int e = beg + t; e < end; e += 512) {
        u32 d = (u32)dst[e];
        u32 b = d >> BKT_SHIFT;
        u32 pos = atomicAdd(&s_cur[b], 1u);          // LDS-only RMW
        u32 packed = (u32)src[e] | ((d & (BKT_NODES - 1)) << 17);
        if (pos < (u32)CAP) {
            s_stage[(b << CAPSH) + pos] = packed;
        } else {
            u32 g = atomicAdd(&s_ovf_n, 1u);         // ~never taken
            if (g < (u32)OVFB) {
                ovfb[((size_t)blk * OVFB + g) * 2]     = packed;
                ovfb[((size_t)blk * OVFB + g) * 2 + 1] = (u32)b;
            }
        }
    }
    __syncthreads();
    // bucket-major flush: bin[b][blk][slot]. quad0 ALWAYS written, count in
    // .x bits[24:28]; quads 1..3 gated on count. Plain stores (NT regressed:
    // L2 retention of bin lines matters for the gather).
    {
        const uint4* sq = (const uint4*)s_stage;
        uint4* gq = (uint4*)bin;
        int nquads = nb << (CAPSH - 2);
        for (int i = t; i < nquads; i += 512) {
            int b  = i >> (CAPSH - 2);
            int k4 = i & ((1 << (CAPSH - 2)) - 1);
            u32 cn = min(s_cur[b], (u32)CAP);
            size_t gidx = (((size_t)b * nsub + blk) << (CAPSH - 2)) + k4;
            if (k4 == 0) {
                uint4 v = sq[i];
                v.x = (v.x & 0x00FFFFFFu) | (cn << 24);
                gq[gidx] = v;
            } else if ((u32)(k4 << 2) < cn) {
                gq[gidx] = sq[i];
            }
        }
    }
    if (t == 0) ovfn[blk] = min(s_ovf_n, (u32)OVFB);
}

// One block per bucket: counts from bin quad0 words -> shfl-scan ->
// sequential gated pack -> sort by dlocal (shfl-scan) -> register
// accumulate (4-way unrolled).
__global__ void __launch_bounds__(512)
k_gather7(const float* __restrict__ x, const u32* __restrict__ bin,
          const u32* __restrict__ ovfb, const u32* __restrict__ ovfn,
          float* __restrict__ out, int n_nodes, int nb, int nsub) {
    __shared__ u32 s_cnt[512];
    __shared__ u32 s_base[513];
    __shared__ u32 s_wsum[8];
    __shared__ u32 s_ent[ECAP];
    __shared__ u32 s_srt[ECAP];
    __shared__ u32 s_off[BKT_NODES + 1];
    __shared__ u32 s_cur[BKT_NODES];
    __shared__ u32 s_has;
    int b = blockIdx.x, t = threadIdx.x;
    int lane = t & 63, wid = t >> 6;
    int node0 = b * BKT_NODES;
    const float4* x4 = (const float4*)x;
    const uint4* bin4 = (const uint4*)bin;
    int q = t & 7;
    int n0 = t >> 3;                       // nodes n0 and n0+64
    float4 a0 = make_float4(0.f, 0.f, 0.f, 0.f);
    float4 a1 = make_float4(0.f, 0.f, 0.f, 0.f);

    // sub-bin counts from bin quad0 words (same lines the pack re-reads)
    u32 c = 0u;
    if (t < nsub) {
        u32 w = bin[((size_t)b * nsub + t) << CAPSH];
        c = (w >> 24) & 0x1Fu;
    }
    u32 myovf = (t < nsub) ? ovfn[t] : 0u;
    s_cnt[t] = c;
    if (t == 0) s_has = 0u;
    // exclusive scan (wave shfl + cross-wave fix)
    u32 s = c;
    #pragma unroll
    for (int off = 1; off < 64; off <<= 1) {
        u32 y = __shfl_up(s, off, 64);
        if (lane >= off) s += y;
    }
    if (lane == 63) s_wsum[wid] = s;
    __syncthreads();
    if (t == 0) {
        u32 run = 0u;
        #pragma unroll
        for (int w = 0; w < 8; ++w) { u32 v = s_wsum[w]; s_wsum[w] = run; run += v; }
    }
    if (myovf) atomicOr(&s_has, 1u);
    __syncthreads();
    u32 incl = s + s_wsum[wid];
    s_base[t] = incl - c;                  // exclusive
    if (t == 511) s_base[512] = incl;
    __syncthreads();

    int subA = 0;
    u32 baseA = 0u;
    while (subA < nsub) {
        // largest subB with base[subB]-baseA <= ECAP
        int lo = subA + 1, hi = nsub;
        while (lo < hi) {
            int mid = (lo + hi + 1) >> 1;
            if (s_base[mid] - baseA <= (u32)ECAP) lo = mid; else hi = mid - 1;
        }
        int subB = lo;
        int m = (int)(s_base[subB] - baseA);

        // pack sub-bins [subA,subB): sequential gated uint4 stream.
        // slot-0 words carry count bits [24:28]; masked at use-sites below.
        {
            int quads = (subB - subA) << (CAPSH - 2);
            size_t qbase = ((size_t)b * nsub + subA) << (CAPSH - 2);
            for (int i = t; i < quads; i += 512) {
                int sub = subA + (i >> (CAPSH - 2));
                int slot0 = (i & ((1 << (CAPSH - 2)) - 1)) << 2;
                u32 cn = s_cnt[sub];
                if ((u32)slot0 < cn) {
                    uint4 v = bin4[qbase + i];
                    u32 base = (s_base[sub] - baseA) + slot0;
                    s_ent[base] = v.x;
                    if ((u32)(slot0 + 1) < cn) s_ent[base + 1] = v.y;
                    if ((u32)(slot0 + 2) < cn) s_ent[base + 2] = v.z;
                    if ((u32)(slot0 + 3) < cn) s_ent[base + 3] = v.w;
                }
            }
        }
        if (t < BKT_NODES) s_cur[t] = 0u;
        __syncthreads();

        // count by dlocal (mask: slot-0 entries carry count bits above 24)
        for (int i = t; i < m; i += 512) atomicAdd(&s_cur[(s_ent[i] >> 17) & 127u], 1u);
        __syncthreads();

        // 128-entry exclusive scan by wave 0 (2 entries/lane, shfl)
        if (wid == 0) {
            u32 v0 = s_cur[2 * lane], v1 = s_cur[2 * lane + 1];
            u32 ps = v0 + v1;
            #pragma unroll
            for (int off = 1; off < 64; off <<= 1) {
                u32 y = __shfl_up(ps, off, 64);
                if (lane >= off) ps += y;
            }
            u32 ex = ps - (v0 + v1);
            s_off[2 * lane] = ex;     s_cur[2 * lane] = ex;
            s_off[2 * lane + 1] = ex + v0; s_cur[2 * lane + 1] = ex + v0;
            if (lane == 63) s_off[BKT_NODES] = ps;
        }
        __syncthreads();

        // rank into s_srt
        for (int i = t; i < m; i += 512) {
            u32 p = s_ent[i];
            u32 pos = atomicAdd(&s_cur[(p >> 17) & 127u], 1u);
            s_srt[pos] = p & 0x1FFFFu;
        }
        __syncthreads();

        // accumulate: 8 lanes share one 128B x-row; 4-way unroll for MLP
        {
            u32 j = s_off[n0], j1 = s_off[n0 + 1];
            for (; j + 3 < j1; j += 4) {
                float4 xa = x4[(size_t)s_srt[j] * 8 + q];
                float4 xb = x4[(size_t)s_srt[j + 1] * 8 + q];
                float4 xc = x4[(size_t)s_srt[j + 2] * 8 + q];
                float4 xd = x4[(size_t)s_srt[j + 3] * 8 + q];
                a0.x += xa.x + xb.x + xc.x + xd.x;
                a0.y += xa.y + xb.y + xc.y + xd.y;
                a0.z += xa.z + xb.z + xc.z + xd.z;
                a0.w += xa.w + xb.w + xc.w + xd.w;
            }
            for (; j < j1; ++j) {
                float4 xa = x4[(size_t)s_srt[j] * 8 + q];
                a0.x += xa.x; a0.y += xa.y; a0.z += xa.z; a0.w += xa.w;
            }
            j = s_off[n0 + 64]; j1 = s_off[n0 + 65];
            for (; j + 3 < j1; j += 4) {
                float4 xa = x4[(size_t)s_srt[j] * 8 + q];
                float4 xb = x4[(size_t)s_srt[j + 1] * 8 + q];
                float4 xc = x4[(size_t)s_srt[j + 2] * 8 + q];
                float4 xd = x4[(size_t)s_srt[j + 3] * 8 + q];
                a1.x += xa.x + xb.x + xc.x + xd.x;
                a1.y += xa.y + xb.y + xc.y + xd.y;
                a1.z += xa.z + xb.z + xc.z + xd.z;
                a1.w += xa.w + xb.w + xc.w + xd.w;
            }
            for (; j < j1; ++j) {
                float4 xa = x4[(size_t)s_srt[j] * 8 + q];
                a1.x += xa.x; a1.y += xa.y; a1.z += xa.z; a1.w += xa.w;
            }
        }
        __syncthreads();
        subA = subB;
        baseA = s_base[subB];
    }

    // replay per-block overflow lists (normally all empty)
    if (s_has) {
        for (int sub = 0; sub < nsub; ++sub) {
            u32 n = ovfn[sub];
            for (u32 i = 0; i < n; ++i) {
                u32 ob = ovfb[((size_t)sub * OVFB + i) * 2 + 1];
                if (ob == (u32)b) {
                    u32 p = ovfb[((size_t)sub * OVFB + i) * 2];
                    u32 dl = (p >> 17) & 127u;
                    if (dl == (u32)n0 || dl == (u32)(n0 + 64)) {
                        float4 xv = x4[(size_t)(p & 0x1FFFFu) * 8 + q];
                        if (dl == (u32)n0) { a0.x += xv.x; a0.y += xv.y; a0.z += xv.z; a0.w += xv.w; }
                        else               { a1.x += xv.x; a1.y += xv.y; a1.z += xv.z; a1.w += xv.w; }
                    }
                }
            }
        }
    }

    float4* o4 = (float4*)out;
    if (node0 + n0 < n_nodes)      o4[(size_t)node0 * 8 + t] = a0;
    if (node0 + n0 + 64 < n_nodes) o4[(size_t)node0 * 8 + 512 + t] = a1;
}

// ---------------- last-resort atomic path ----------------

__global__ void __launch_bounds__(256)
mp_zero_kernel(float* __restrict__ out, int n) {
    int i = blockIdx.x * blockDim.x + threadIdx.x;
    if (i < n) out[i] = 0.0f;
}

__global__ void __launch_bounds__(256)
mp_scatter_kernel(const float* __restrict__ x, const int* __restrict__ src,
                  const int* __restrict__ dst, float* __restrict__ out,
                  int n_edges) {
    int idx = blockIdx.x * blockDim.x + threadIdx.x;
    if (idx >= n_edges * 8) return;
    int e = idx >> 3;
    int c = idx & 7;
    const float4 v = *reinterpret_cast<const float4*>(x + (size_t)src[e] * D_FEAT + c * 4);
    float* o = out + (size_t)dst[e] * D_FEAT + c * 4;
    unsafeAtomicAdd(o + 0, v.x);
    unsafeAtomicAdd(o + 1, v.y);
    unsafeAtomicAdd(o + 2, v.z);
    unsafeAtomicAdd(o + 3, v.w);
}

// ==================== launch ====================

extern "C" void kernel_launch(void* const* d_in, const int* in_sizes, int n_in,
                              void* d_out, int out_size, void* d_ws, size_t ws_size,
                              hipStream_t stream) {
    const float* x = (const float*)d_in[0];
    const int* edge_index = (const int*)d_in[1];
    int n_edges = in_sizes[1] / 2;
    const int* src = edge_index;            // row 0: source j
    const int* dst = edge_index + n_edges;  // row 1: target i
    float* out = (float*)d_out;
    int n_nodes = out_size / D_FEAT;

    int nb = (n_nodes + BKT_NODES - 1) >> BKT_SHIFT;     // 782

    // dynamic LDS for scatter: nb*CAP stage + nb cursors
    size_t sc_lds = ((size_t)nb * CAP + nb) * sizeof(u32);   // 53.2 KB @ nb=782

    if (n_nodes <= (1 << 17) && sc_lds <= 64 * 1024) {
        const int ncand[3] = {512, 384, 256};
        for (int ci = 0; ci < 3; ++ci) {
            int nsub = ncand[ci];
            int chunk = (n_edges + nsub - 1) / nsub;
            size_t need = (512                                // ovfn
                           + 2 * (size_t)nsub * OVFB          // ovfb
                           + (((size_t)nb * nsub) << CAPSH))  // bin (bucket-major)
                          * sizeof(u32);
            if (need > ws_size) continue;

            u32* ovfn = (u32*)d_ws;
            u32* ovfb = ovfn + 512;
            u32* bin  = ovfb + 2 * (size_t)nsub * OVFB;

            k_scatter6<<<nsub, 512, sc_lds, stream>>>(src, dst, bin, ovfb, ovfn,
                                                      n_edges, nb, nsub, chunk);
            k_gather7<<<nb, 512, 0, stream>>>(x, bin, ovfb, ovfn, out,
                                              n_nodes, nb, nsub);
            return;
        }
    }

    // last-resort: atomic path
    mp_zero_kernel<<<(out_size + 255) / 256, 256, 0, stream>>>(out, out_size);
    int total_thr = n_edges * 8;
    mp_scatter_kernel<<<(total_thr + 255) / 256, 256, 0, stream>>>(x, src, dst, out, n_edges);
}